// Round 1
// baseline (696.952 us; speedup 1.0000x reference)
//
#include <hip/hip_runtime.h>

#define N_LOC   500000
#define N_CAT   5000
#define N_EDGES 2000000
#define DIM     128
#define NEG_SLOPE 0.2f

// ---------------- CSR build ----------------

__global__ void hist_kernel(const int* __restrict__ dst, int* __restrict__ cnt, int n) {
    int i = blockIdx.x * blockDim.x + threadIdx.x;
    if (i < n) atomicAdd(&cnt[dst[i]], 1);
}

// single-block exclusive scan of cnt[0..N_CAT) -> offsets[0..N_CAT]
__global__ void scan_kernel(const int* __restrict__ cnt, int* __restrict__ offsets) {
    __shared__ int buf[256];
    __shared__ int s_running;
    int t = threadIdx.x;
    if (t == 0) { offsets[0] = 0; s_running = 0; }
    __syncthreads();
    for (int base = 0; base < N_CAT; base += 256) {
        int i = base + t;
        int v = (i < N_CAT) ? cnt[i] : 0;
        buf[t] = v;
        __syncthreads();
        for (int off = 1; off < 256; off <<= 1) {
            int x = buf[t];
            int y = (t >= off) ? buf[t - off] : 0;
            __syncthreads();
            buf[t] = x + y;
            __syncthreads();
        }
        int incl = buf[t];
        int run = s_running;
        if (i < N_CAT) offsets[i + 1] = run + incl;
        __syncthreads();
        if (t == 255) s_running = run + incl;
        __syncthreads();
    }
}

__global__ void fill_kernel(const int* __restrict__ src, const int* __restrict__ dst,
                            const int* __restrict__ offsets, int* __restrict__ cursor,
                            int* __restrict__ csr_src, int n) {
    int i = blockIdx.x * blockDim.x + threadIdx.x;
    if (i < n) {
        int d = dst[i];
        int p = atomicAdd(&cursor[d], 1);
        csr_src[offsets[d] + p] = src[i];
    }
}

// ---------------- aggregation (atomics-free) ----------------
// one block per cat; 128 threads = 4 edge-groups x 32 lanes; each lane holds float4 (4 dims)
__launch_bounds__(128)
__global__ void agg_kernel(const float* __restrict__ loc, const int* __restrict__ csr_src,
                           const int* __restrict__ offsets, float* __restrict__ agg) {
    int c = blockIdx.x;
    int t = threadIdx.x;
    int g = t >> 5;       // edge group 0..3
    int l = t & 31;       // dim group: dims 4l..4l+3
    int beg = offsets[c];
    int end = offsets[c + 1];
    float4 acc = make_float4(0.f, 0.f, 0.f, 0.f);
    #pragma unroll 4
    for (int e = beg + g; e < end; e += 4) {
        int s = csr_src[e];
        float4 v = ((const float4*)(loc + (size_t)s * DIM))[l];
        acc.x += v.x; acc.y += v.y; acc.z += v.z; acc.w += v.w;
    }
    __shared__ float4 sacc[128];
    sacc[t] = acc;
    __syncthreads();
    if (g == 0) {
        float4 a = sacc[l], b = sacc[32 + l], c2 = sacc[64 + l], d = sacc[96 + l];
        float4 r = make_float4(a.x + b.x + c2.x + d.x,
                               a.y + b.y + c2.y + d.y,
                               a.z + b.z + c2.z + d.z,
                               a.w + b.w + c2.w + d.w);
        ((float4*)(agg + (size_t)c * DIM))[l] = r;
    }
}

// ---------------- fallback: atomic scatter directly into d_out ----------------
__global__ void zero_kernel(float* p, int n) {
    int i = blockIdx.x * blockDim.x + threadIdx.x;
    if (i < n) p[i] = 0.f;
}

__launch_bounds__(128)
__global__ void scatter_atomic_kernel(const float* __restrict__ loc, const int* __restrict__ src,
                                      const int* __restrict__ dst, float* __restrict__ agg) {
    int e = blockIdx.x;
    int d = threadIdx.x;
    int s = src[e];
    int c = dst[e];
    atomicAdd(&agg[(size_t)c * DIM + d], loc[(size_t)s * DIM + d]);
}

// ---------------- linear + LeakyReLU ----------------
// 8 cats per block, 256 threads; W staged in LDS with +1-pad (129) => conflict-free.
// Safe in-place (agg == out): each block stages its own 8 rows into LDS before writing.
#define CATS_PER_BLOCK 8
__launch_bounds__(256)
__global__ void gemm_lrelu_kernel(const float* __restrict__ agg, const float* __restrict__ W,
                                  const float* __restrict__ b, float* __restrict__ out) {
    __shared__ float sW[DIM * 129];
    __shared__ float sA[CATS_PER_BLOCK * DIM];
    int t = threadIdx.x;
    int cbase = blockIdx.x * CATS_PER_BLOCK;
    for (int i = t; i < DIM * DIM; i += 256) {
        int j = i >> 7, k = i & 127;
        sW[j * 129 + k] = W[i];
    }
    for (int i = t; i < CATS_PER_BLOCK * DIM; i += 256) {
        sA[i] = agg[(size_t)cbase * DIM + i];
    }
    __syncthreads();
    int j = t & 127;   // output dim
    int cc = t >> 7;   // 0..1
    float acc0 = 0.f, acc1 = 0.f, acc2 = 0.f, acc3 = 0.f;
    for (int k = 0; k < DIM; ++k) {
        float w = sW[j * 129 + k];
        acc0 += w * sA[(cc + 0) * DIM + k];
        acc1 += w * sA[(cc + 2) * DIM + k];
        acc2 += w * sA[(cc + 4) * DIM + k];
        acc3 += w * sA[(cc + 6) * DIM + k];
    }
    float bj = b[j];
    float r0 = acc0 + bj, r1 = acc1 + bj, r2 = acc2 + bj, r3 = acc3 + bj;
    r0 = r0 > 0.f ? r0 : NEG_SLOPE * r0;
    r1 = r1 > 0.f ? r1 : NEG_SLOPE * r1;
    r2 = r2 > 0.f ? r2 : NEG_SLOPE * r2;
    r3 = r3 > 0.f ? r3 : NEG_SLOPE * r3;
    out[(size_t)(cbase + cc + 0) * DIM + j] = r0;
    out[(size_t)(cbase + cc + 2) * DIM + j] = r1;
    out[(size_t)(cbase + cc + 4) * DIM + j] = r2;
    out[(size_t)(cbase + cc + 6) * DIM + j] = r3;
}

extern "C" void kernel_launch(void* const* d_in, const int* in_sizes, int n_in,
                              void* d_out, int out_size, void* d_ws, size_t ws_size,
                              hipStream_t stream) {
    const float* loc  = (const float*)d_in[0];
    const float* W    = (const float*)d_in[1];
    const float* bias = (const float*)d_in[2];
    const int*   esrc = (const int*)d_in[3];
    const int*   edst = (const int*)d_in[4];
    float* out = (float*)d_out;

    const int PAD = 5008;  // padded N_CAT slots
    size_t need_bytes = (size_t)(3 * PAD + N_EDGES) * sizeof(int)
                      + (size_t)N_CAT * DIM * sizeof(float);

    if (ws_size >= need_bytes) {
        // -------- CSR path --------
        int* counts  = (int*)d_ws;            // [PAD]
        int* cursor  = counts + PAD;          // [PAD]
        int* offsets = cursor + PAD;          // [N_CAT+1]
        int* csr_src = offsets + PAD;         // [N_EDGES]
        float* agg   = (float*)(csr_src + N_EDGES);  // [N_CAT*DIM]

        hipMemsetAsync(counts, 0, (size_t)2 * PAD * sizeof(int), stream);  // counts + cursor

        int threads = 256;
        int eblocks = (N_EDGES + threads - 1) / threads;
        hist_kernel<<<eblocks, threads, 0, stream>>>(edst, counts, N_EDGES);
        scan_kernel<<<1, 256, 0, stream>>>(counts, offsets);
        fill_kernel<<<eblocks, threads, 0, stream>>>(esrc, edst, offsets, cursor, csr_src, N_EDGES);
        agg_kernel<<<N_CAT, 128, 0, stream>>>(loc, csr_src, offsets, agg);
        gemm_lrelu_kernel<<<N_CAT / CATS_PER_BLOCK, 256, 0, stream>>>(agg, W, bias, out);
    } else {
        // -------- fallback: atomic scatter into d_out, in-place GEMM --------
        int n = N_CAT * DIM;
        zero_kernel<<<(n + 255) / 256, 256, 0, stream>>>(out, n);
        scatter_atomic_kernel<<<N_EDGES, DIM, 0, stream>>>(loc, esrc, edst, out);
        gemm_lrelu_kernel<<<N_CAT / CATS_PER_BLOCK, 256, 0, stream>>>(out, W, bias, out);
    }
}

// Round 2
// 607.636 us; speedup vs baseline: 1.1470x; 1.1470x over previous
//
#include <hip/hip_runtime.h>

#define N_LOC   500000
#define N_CAT   5000
#define N_EDGES 2000000
#define DIM     128
#define NEG_SLOPE 0.2f
#define PAD     5008

// ---------------- CSR build ----------------

// hist with rank: one atomic pass produces both counts and per-edge rank
__global__ void hist_rank_kernel(const int* __restrict__ dst, int* __restrict__ cnt,
                                 int* __restrict__ rank, int n) {
    int i = blockIdx.x * blockDim.x + threadIdx.x;
    if (i < n) rank[i] = atomicAdd(&cnt[dst[i]], 1);
}

__global__ void hist_kernel(const int* __restrict__ dst, int* __restrict__ cnt, int n) {
    int i = blockIdx.x * blockDim.x + threadIdx.x;
    if (i < n) atomicAdd(&cnt[dst[i]], 1);
}

// single-block 1024-thread shfl-based exclusive scan of cnt[0..N_CAT) -> offsets[0..N_CAT]
__launch_bounds__(1024)
__global__ void scan_kernel(const int* __restrict__ cnt, int* __restrict__ offsets) {
    __shared__ int wsum[16];
    __shared__ int woff[16];
    __shared__ int total_s;
    __shared__ int running_s;
    int t = threadIdx.x;
    int lane = t & 63, w = t >> 6;
    if (t == 0) { running_s = 0; offsets[0] = 0; }
    __syncthreads();
    for (int base = 0; base < N_CAT; base += 1024) {
        int i = base + t;
        int v = (i < N_CAT) ? cnt[i] : 0;
        int incl = v;
        #pragma unroll
        for (int off = 1; off < 64; off <<= 1) {
            int x = __shfl_up(incl, off, 64);
            if (lane >= off) incl += x;
        }
        if (lane == 63) wsum[w] = incl;
        __syncthreads();
        if (w == 0 && lane < 16) {
            int s = wsum[lane];
            int e = s;
            #pragma unroll
            for (int off = 1; off < 16; off <<= 1) {
                int x = __shfl_up(e, off, 64);
                if (lane >= off) e += x;
            }
            woff[lane] = e - s;       // exclusive wave offset
            if (lane == 15) total_s = e;
        }
        __syncthreads();
        int run = running_s;
        if (i < N_CAT) offsets[i + 1] = run + woff[w] + incl;
        __syncthreads();
        if (t == 0) running_s = run + total_s;
        __syncthreads();
    }
}

// atomic-free fill using precomputed rank
__global__ void fill_rank_kernel(const int* __restrict__ src, const int* __restrict__ dst,
                                 const int* __restrict__ rank, const int* __restrict__ offsets,
                                 int* __restrict__ csr_src, int n) {
    int i = blockIdx.x * blockDim.x + threadIdx.x;
    if (i < n) csr_src[offsets[dst[i]] + rank[i]] = src[i];
}

__global__ void fill_cursor_kernel(const int* __restrict__ src, const int* __restrict__ dst,
                                   const int* __restrict__ offsets, int* __restrict__ cursor,
                                   int* __restrict__ csr_src, int n) {
    int i = blockIdx.x * blockDim.x + threadIdx.x;
    if (i < n) {
        int d = dst[i];
        int p = atomicAdd(&cursor[d], 1);
        csr_src[offsets[d] + p] = src[i];
    }
}

// W[j][k] -> WT[k][j] (tiny, once per launch; stays hot in L2)
__global__ void transpose_kernel(const float* __restrict__ W, float* __restrict__ WT) {
    int j = blockIdx.x;      // 128 blocks
    int k = threadIdx.x;     // 128 threads, coalesced read of row j
    WT[k * DIM + j] = W[j * DIM + k];
}

// ---------------- fused aggregate + linear + LeakyReLU ----------------
// one block per cat; 256 threads = 8 edge-groups x 32 lanes (gather phase),
// then 2 threads per output dim (matvec phase, WT coalesced).
__launch_bounds__(256)
__global__ void agg_fused_kernel(const float* __restrict__ loc, const int* __restrict__ csr_src,
                                 const int* __restrict__ offsets, const float* __restrict__ WT,
                                 const float* __restrict__ bias, float* __restrict__ out) {
    __shared__ float4 sacc[256];   // 4 KB, reused as float sred[1024] later
    __shared__ float  srow[DIM];
    int c = blockIdx.x;
    int t = threadIdx.x;
    int g = t >> 5;       // edge group 0..7
    int l = t & 31;       // dim group: dims 4l..4l+3
    int beg = offsets[c];
    int end = offsets[c + 1];
    float4 acc = make_float4(0.f, 0.f, 0.f, 0.f);
    for (int e = beg + g; e < end; e += 8) {
        int s = csr_src[e];
        float4 v = ((const float4*)(loc + (size_t)s * DIM))[l];
        acc.x += v.x; acc.y += v.y; acc.z += v.z; acc.w += v.w;
    }
    sacc[t] = acc;
    __syncthreads();
    if (t < 128) {
        float4 a = sacc[t], b = sacc[t + 128];
        sacc[t] = make_float4(a.x + b.x, a.y + b.y, a.z + b.z, a.w + b.w);
    }
    __syncthreads();
    if (t < 64) {
        float4 a = sacc[t], b = sacc[t + 64];
        sacc[t] = make_float4(a.x + b.x, a.y + b.y, a.z + b.z, a.w + b.w);
    }
    __syncthreads();
    if (t < 32) {
        float4 a = sacc[t], b = sacc[t + 32];
        srow[4 * t + 0] = a.x + b.x;
        srow[4 * t + 1] = a.y + b.y;
        srow[4 * t + 2] = a.z + b.z;
        srow[4 * t + 3] = a.w + b.w;
    }
    __syncthreads();
    // matvec: j = t&127, half h = t>>7 covers k in [h*64, h*64+64)
    int j = t & 127;
    int h = t >> 7;
    float a0 = 0.f, a1 = 0.f, a2 = 0.f, a3 = 0.f;
    int k0 = h * 64;
    #pragma unroll 4
    for (int k = 0; k < 64; k += 4) {
        a0 += WT[(k0 + k + 0) * DIM + j] * srow[k0 + k + 0];
        a1 += WT[(k0 + k + 1) * DIM + j] * srow[k0 + k + 1];
        a2 += WT[(k0 + k + 2) * DIM + j] * srow[k0 + k + 2];
        a3 += WT[(k0 + k + 3) * DIM + j] * srow[k0 + k + 3];
    }
    float* sred = (float*)sacc;
    sred[t] = (a0 + a1) + (a2 + a3);
    __syncthreads();
    if (t < 128) {
        float v = sred[t] + sred[t + 128] + bias[t];
        v = v > 0.f ? v : NEG_SLOPE * v;
        out[(size_t)c * DIM + t] = v;
    }
}

// ---------------- fallback: atomic scatter directly into d_out ----------------
__global__ void zero_kernel(float* p, int n) {
    int i = blockIdx.x * blockDim.x + threadIdx.x;
    if (i < n) p[i] = 0.f;
}

__launch_bounds__(128)
__global__ void scatter_atomic_kernel(const float* __restrict__ loc, const int* __restrict__ src,
                                      const int* __restrict__ dst, float* __restrict__ agg) {
    int e = blockIdx.x;
    int d = threadIdx.x;
    int s = src[e];
    int c = dst[e];
    atomicAdd(&agg[(size_t)c * DIM + d], loc[(size_t)s * DIM + d]);
}

#define CATS_PER_BLOCK 8
__launch_bounds__(256)
__global__ void gemm_lrelu_kernel(const float* __restrict__ agg, const float* __restrict__ W,
                                  const float* __restrict__ b, float* __restrict__ out) {
    __shared__ float sW[DIM * 129];
    __shared__ float sA[CATS_PER_BLOCK * DIM];
    int t = threadIdx.x;
    int cbase = blockIdx.x * CATS_PER_BLOCK;
    for (int i = t; i < DIM * DIM; i += 256) {
        int j = i >> 7, k = i & 127;
        sW[j * 129 + k] = W[i];
    }
    for (int i = t; i < CATS_PER_BLOCK * DIM; i += 256) {
        sA[i] = agg[(size_t)cbase * DIM + i];
    }
    __syncthreads();
    int j = t & 127;
    int cc = t >> 7;
    float acc0 = 0.f, acc1 = 0.f, acc2 = 0.f, acc3 = 0.f;
    for (int k = 0; k < DIM; ++k) {
        float w = sW[j * 129 + k];
        acc0 += w * sA[(cc + 0) * DIM + k];
        acc1 += w * sA[(cc + 2) * DIM + k];
        acc2 += w * sA[(cc + 4) * DIM + k];
        acc3 += w * sA[(cc + 6) * DIM + k];
    }
    float bj = b[j];
    float r0 = acc0 + bj, r1 = acc1 + bj, r2 = acc2 + bj, r3 = acc3 + bj;
    r0 = r0 > 0.f ? r0 : NEG_SLOPE * r0;
    r1 = r1 > 0.f ? r1 : NEG_SLOPE * r1;
    r2 = r2 > 0.f ? r2 : NEG_SLOPE * r2;
    r3 = r3 > 0.f ? r3 : NEG_SLOPE * r3;
    out[(size_t)(cbase + cc + 0) * DIM + j] = r0;
    out[(size_t)(cbase + cc + 2) * DIM + j] = r1;
    out[(size_t)(cbase + cc + 4) * DIM + j] = r2;
    out[(size_t)(cbase + cc + 6) * DIM + j] = r3;
}

extern "C" void kernel_launch(void* const* d_in, const int* in_sizes, int n_in,
                              void* d_out, int out_size, void* d_ws, size_t ws_size,
                              hipStream_t stream) {
    const float* loc  = (const float*)d_in[0];
    const float* W    = (const float*)d_in[1];
    const float* bias = (const float*)d_in[2];
    const int*   esrc = (const int*)d_in[3];
    const int*   edst = (const int*)d_in[4];
    float* out = (float*)d_out;

    const int threads = 256;
    const int eblocks = (N_EDGES + threads - 1) / threads;

    size_t need_rank = ((size_t)2 * PAD + 2 * (size_t)N_EDGES + DIM * DIM) * sizeof(int);
    size_t need_cur  = ((size_t)3 * PAD + (size_t)N_EDGES + DIM * DIM) * sizeof(int);

    if (ws_size >= need_rank) {
        // -------- path A: rank-based (atomic-free fill) --------
        int* counts  = (int*)d_ws;                 // [PAD]
        int* offsets = counts + PAD;               // [N_CAT+1]
        float* WT    = (float*)(offsets + PAD);    // [128*128]
        int* rank    = (int*)(WT + DIM * DIM);     // [N_EDGES]
        int* csr_src = rank + N_EDGES;             // [N_EDGES]

        hipMemsetAsync(counts, 0, (size_t)PAD * sizeof(int), stream);
        transpose_kernel<<<DIM, DIM, 0, stream>>>(W, WT);
        hist_rank_kernel<<<eblocks, threads, 0, stream>>>(edst, counts, rank, N_EDGES);
        scan_kernel<<<1, 1024, 0, stream>>>(counts, offsets);
        fill_rank_kernel<<<eblocks, threads, 0, stream>>>(esrc, edst, rank, offsets, csr_src, N_EDGES);
        agg_fused_kernel<<<N_CAT, 256, 0, stream>>>(loc, csr_src, offsets, WT, bias, out);
    } else if (ws_size >= need_cur) {
        // -------- path B: cursor-based fill --------
        int* counts  = (int*)d_ws;                 // [PAD]
        int* cursor  = counts + PAD;               // [PAD]
        int* offsets = cursor + PAD;               // [N_CAT+1]
        float* WT    = (float*)(offsets + PAD);    // [128*128]
        int* csr_src = (int*)(WT + DIM * DIM);     // [N_EDGES]

        hipMemsetAsync(counts, 0, (size_t)2 * PAD * sizeof(int), stream);
        transpose_kernel<<<DIM, DIM, 0, stream>>>(W, WT);
        hist_kernel<<<eblocks, threads, 0, stream>>>(edst, counts, N_EDGES);
        scan_kernel<<<1, 1024, 0, stream>>>(counts, offsets);
        fill_cursor_kernel<<<eblocks, threads, 0, stream>>>(esrc, edst, offsets, cursor, csr_src, N_EDGES);
        agg_fused_kernel<<<N_CAT, 256, 0, stream>>>(loc, csr_src, offsets, WT, bias, out);
    } else {
        // -------- fallback: atomic scatter into d_out, in-place GEMM --------
        int n = N_CAT * DIM;
        zero_kernel<<<(n + 255) / 256, 256, 0, stream>>>(out, n);
        scatter_atomic_kernel<<<N_EDGES, DIM, 0, stream>>>(loc, esrc, edst, out);
        gemm_lrelu_kernel<<<N_CAT / CATS_PER_BLOCK, 256, 0, stream>>>(out, W, bias, out);
    }
}

// Round 3
// 504.145 us; speedup vs baseline: 1.3824x; 1.2053x over previous
//
#include <hip/hip_runtime.h>

#define N_LOC   500000
#define N_CAT   5000
#define N_EDGES 2000000
#define DIM     128
#define NEG_SLOPE 0.2f
#define PAD     5008
#define NB      256                      // blocks in counting-sort phase
#define EPB     ((N_EDGES + NB - 1) / NB)  // edges per block = 7813

// ================= counting-sort CSR build (zero global atomics) =================

// K1: per-block LDS histogram; rank[i] = local rank within block; bhist[b][c] = block count
__launch_bounds__(1024)
__global__ void blockhist_kernel(const int* __restrict__ edst, int* __restrict__ rank,
                                 int* __restrict__ bhist) {
    __shared__ int lh[N_CAT];
    int b = blockIdx.x, t = threadIdx.x;
    for (int c = t; c < N_CAT; c += 1024) lh[c] = 0;
    __syncthreads();
    int s = b * EPB;
    int e = min(s + EPB, N_EDGES);
    for (int i = s + t; i < e; i += 1024)
        rank[i] = atomicAdd(&lh[edst[i]], 1);
    __syncthreads();
    for (int c = t; c < N_CAT; c += 1024)
        bhist[(size_t)b * N_CAT + c] = lh[c];
}

// K2: for each cat, exclusive prefix over the 256 block counts (in place) + total
__launch_bounds__(256)
__global__ void blockscan_kernel(int* __restrict__ bhist, int* __restrict__ tot) {
    int c = blockIdx.x * 256 + threadIdx.x;
    if (c >= N_CAT) return;
    int run = 0;
    for (int b0 = 0; b0 < NB; b0 += 8) {
        int v0 = bhist[(size_t)(b0 + 0) * N_CAT + c];
        int v1 = bhist[(size_t)(b0 + 1) * N_CAT + c];
        int v2 = bhist[(size_t)(b0 + 2) * N_CAT + c];
        int v3 = bhist[(size_t)(b0 + 3) * N_CAT + c];
        int v4 = bhist[(size_t)(b0 + 4) * N_CAT + c];
        int v5 = bhist[(size_t)(b0 + 5) * N_CAT + c];
        int v6 = bhist[(size_t)(b0 + 6) * N_CAT + c];
        int v7 = bhist[(size_t)(b0 + 7) * N_CAT + c];
        bhist[(size_t)(b0 + 0) * N_CAT + c] = run; run += v0;
        bhist[(size_t)(b0 + 1) * N_CAT + c] = run; run += v1;
        bhist[(size_t)(b0 + 2) * N_CAT + c] = run; run += v2;
        bhist[(size_t)(b0 + 3) * N_CAT + c] = run; run += v3;
        bhist[(size_t)(b0 + 4) * N_CAT + c] = run; run += v4;
        bhist[(size_t)(b0 + 5) * N_CAT + c] = run; run += v5;
        bhist[(size_t)(b0 + 6) * N_CAT + c] = run; run += v6;
        bhist[(size_t)(b0 + 7) * N_CAT + c] = run; run += v7;
    }
    tot[c] = run;
}

// single-block 1024-thread shfl-based exclusive scan of tot[0..N_CAT) -> offsets[0..N_CAT]
__launch_bounds__(1024)
__global__ void scan_kernel(const int* __restrict__ cnt, int* __restrict__ offsets) {
    __shared__ int wsum[16];
    __shared__ int woff[16];
    __shared__ int total_s;
    __shared__ int running_s;
    int t = threadIdx.x;
    int lane = t & 63, w = t >> 6;
    if (t == 0) { running_s = 0; offsets[0] = 0; }
    __syncthreads();
    for (int base = 0; base < N_CAT; base += 1024) {
        int i = base + t;
        int v = (i < N_CAT) ? cnt[i] : 0;
        int incl = v;
        #pragma unroll
        for (int off = 1; off < 64; off <<= 1) {
            int x = __shfl_up(incl, off, 64);
            if (lane >= off) incl += x;
        }
        if (lane == 63) wsum[w] = incl;
        __syncthreads();
        if (w == 0 && lane < 16) {
            int s = wsum[lane];
            int e = s;
            #pragma unroll
            for (int off = 1; off < 16; off <<= 1) {
                int x = __shfl_up(e, off, 64);
                if (lane >= off) e += x;
            }
            woff[lane] = e - s;
            if (lane == 15) total_s = e;
        }
        __syncthreads();
        int run = running_s;
        if (i < N_CAT) offsets[i + 1] = run + woff[w] + incl;
        __syncthreads();
        if (t == 0) running_s = run + total_s;
        __syncthreads();
    }
}

// K3: atomic-free scatter fill
__global__ void fill2_kernel(const int* __restrict__ esrc, const int* __restrict__ edst,
                             const int* __restrict__ rank, const int* __restrict__ offsets,
                             const int* __restrict__ bhist, int* __restrict__ csr_src) {
    int i = blockIdx.x * blockDim.x + threadIdx.x;
    if (i < N_EDGES) {
        int c = edst[i];
        int b = i / EPB;
        csr_src[offsets[c] + bhist[(size_t)b * N_CAT + c] + rank[i]] = esrc[i];
    }
}

// W[j][k] -> WT[k][j]
__global__ void transpose_kernel(const float* __restrict__ W, float* __restrict__ WT) {
    int j = blockIdx.x;
    int k = threadIdx.x;
    WT[k * DIM + j] = W[j * DIM + k];
}

// ================= fused aggregate + linear + LeakyReLU =================
// one block per cat; 8 groups x 32 lanes; each group owns a CONTIGUOUS csr range,
// manually unrolled x4 -> 4 independent float4 row loads in flight per lane.
__launch_bounds__(256)
__global__ void agg_fused_kernel(const float* __restrict__ loc, const int* __restrict__ csr_src,
                                 const int* __restrict__ offsets, const float* __restrict__ WT,
                                 const float* __restrict__ bias, float* __restrict__ out) {
    __shared__ float4 sacc[256];   // 4 KB, reused as float sred[1024]
    __shared__ float  srow[DIM];
    int c = blockIdx.x;
    int t = threadIdx.x;
    int g = t >> 5;
    int l = t & 31;
    int beg = offsets[c];
    int end = offsets[c + 1];
    int cnt = end - beg;
    int per = (cnt + 7) >> 3;            // edges per group
    int gbeg = beg + g * per;
    int gend = min(gbeg + per, end);

    float4 a0 = make_float4(0.f, 0.f, 0.f, 0.f);
    float4 a1 = make_float4(0.f, 0.f, 0.f, 0.f);
    float4 a2 = make_float4(0.f, 0.f, 0.f, 0.f);
    float4 a3 = make_float4(0.f, 0.f, 0.f, 0.f);
    int e = gbeg;
    for (; e + 4 <= gend; e += 4) {
        int s0 = csr_src[e + 0];
        int s1 = csr_src[e + 1];
        int s2 = csr_src[e + 2];
        int s3 = csr_src[e + 3];
        float4 v0 = ((const float4*)(loc + (size_t)s0 * DIM))[l];
        float4 v1 = ((const float4*)(loc + (size_t)s1 * DIM))[l];
        float4 v2 = ((const float4*)(loc + (size_t)s2 * DIM))[l];
        float4 v3 = ((const float4*)(loc + (size_t)s3 * DIM))[l];
        a0.x += v0.x; a0.y += v0.y; a0.z += v0.z; a0.w += v0.w;
        a1.x += v1.x; a1.y += v1.y; a1.z += v1.z; a1.w += v1.w;
        a2.x += v2.x; a2.y += v2.y; a2.z += v2.z; a2.w += v2.w;
        a3.x += v3.x; a3.y += v3.y; a3.z += v3.z; a3.w += v3.w;
    }
    for (; e < gend; ++e) {
        int s = csr_src[e];
        float4 v = ((const float4*)(loc + (size_t)s * DIM))[l];
        a0.x += v.x; a0.y += v.y; a0.z += v.z; a0.w += v.w;
    }
    float4 acc = make_float4((a0.x + a1.x) + (a2.x + a3.x),
                             (a0.y + a1.y) + (a2.y + a3.y),
                             (a0.z + a1.z) + (a2.z + a3.z),
                             (a0.w + a1.w) + (a2.w + a3.w));
    sacc[t] = acc;
    __syncthreads();
    if (t < 128) {
        float4 a = sacc[t], b = sacc[t + 128];
        sacc[t] = make_float4(a.x + b.x, a.y + b.y, a.z + b.z, a.w + b.w);
    }
    __syncthreads();
    if (t < 64) {
        float4 a = sacc[t], b = sacc[t + 64];
        sacc[t] = make_float4(a.x + b.x, a.y + b.y, a.z + b.z, a.w + b.w);
    }
    __syncthreads();
    if (t < 32) {
        float4 a = sacc[t], b = sacc[t + 32];
        srow[4 * t + 0] = a.x + b.x;
        srow[4 * t + 1] = a.y + b.y;
        srow[4 * t + 2] = a.z + b.z;
        srow[4 * t + 3] = a.w + b.w;
    }
    __syncthreads();
    // matvec: j = t&127, half h = t>>7 covers k in [h*64, h*64+64)
    int j = t & 127;
    int h = t >> 7;
    float m0 = 0.f, m1 = 0.f, m2 = 0.f, m3 = 0.f;
    int k0 = h * 64;
    #pragma unroll 4
    for (int k = 0; k < 64; k += 4) {
        m0 += WT[(k0 + k + 0) * DIM + j] * srow[k0 + k + 0];
        m1 += WT[(k0 + k + 1) * DIM + j] * srow[k0 + k + 1];
        m2 += WT[(k0 + k + 2) * DIM + j] * srow[k0 + k + 2];
        m3 += WT[(k0 + k + 3) * DIM + j] * srow[k0 + k + 3];
    }
    float* sred = (float*)sacc;
    sred[t] = (m0 + m1) + (m2 + m3);
    __syncthreads();
    if (t < 128) {
        float v = sred[t] + sred[t + 128] + bias[t];
        v = v > 0.f ? v : NEG_SLOPE * v;
        out[(size_t)c * DIM + t] = v;
    }
}

// ================= fallback paths =================

__global__ void hist_rank_kernel(const int* __restrict__ dst, int* __restrict__ cnt,
                                 int* __restrict__ rank, int n) {
    int i = blockIdx.x * blockDim.x + threadIdx.x;
    if (i < n) rank[i] = atomicAdd(&cnt[dst[i]], 1);
}

__global__ void fill_rank_kernel(const int* __restrict__ src, const int* __restrict__ dst,
                                 const int* __restrict__ rank, const int* __restrict__ offsets,
                                 int* __restrict__ csr_src, int n) {
    int i = blockIdx.x * blockDim.x + threadIdx.x;
    if (i < n) csr_src[offsets[dst[i]] + rank[i]] = src[i];
}

__global__ void zero_kernel(float* p, int n) {
    int i = blockIdx.x * blockDim.x + threadIdx.x;
    if (i < n) p[i] = 0.f;
}

__launch_bounds__(128)
__global__ void scatter_atomic_kernel(const float* __restrict__ loc, const int* __restrict__ src,
                                      const int* __restrict__ dst, float* __restrict__ agg) {
    int e = blockIdx.x;
    int d = threadIdx.x;
    int s = src[e];
    int c = dst[e];
    atomicAdd(&agg[(size_t)c * DIM + d], loc[(size_t)s * DIM + d]);
}

#define CATS_PER_BLOCK 8
__launch_bounds__(256)
__global__ void gemm_lrelu_kernel(const float* __restrict__ agg, const float* __restrict__ W,
                                  const float* __restrict__ b, float* __restrict__ out) {
    __shared__ float sW[DIM * 129];
    __shared__ float sA[CATS_PER_BLOCK * DIM];
    int t = threadIdx.x;
    int cbase = blockIdx.x * CATS_PER_BLOCK;
    for (int i = t; i < DIM * DIM; i += 256) {
        int j = i >> 7, k = i & 127;
        sW[j * 129 + k] = W[i];
    }
    for (int i = t; i < CATS_PER_BLOCK * DIM; i += 256) {
        sA[i] = agg[(size_t)cbase * DIM + i];
    }
    __syncthreads();
    int j = t & 127;
    int cc = t >> 7;
    float acc0 = 0.f, acc1 = 0.f, acc2 = 0.f, acc3 = 0.f;
    for (int k = 0; k < DIM; ++k) {
        float w = sW[j * 129 + k];
        acc0 += w * sA[(cc + 0) * DIM + k];
        acc1 += w * sA[(cc + 2) * DIM + k];
        acc2 += w * sA[(cc + 4) * DIM + k];
        acc3 += w * sA[(cc + 6) * DIM + k];
    }
    float bj = b[j];
    float r0 = acc0 + bj, r1 = acc1 + bj, r2 = acc2 + bj, r3 = acc3 + bj;
    r0 = r0 > 0.f ? r0 : NEG_SLOPE * r0;
    r1 = r1 > 0.f ? r1 : NEG_SLOPE * r1;
    r2 = r2 > 0.f ? r2 : NEG_SLOPE * r2;
    r3 = r3 > 0.f ? r3 : NEG_SLOPE * r3;
    out[(size_t)(cbase + cc + 0) * DIM + j] = r0;
    out[(size_t)(cbase + cc + 2) * DIM + j] = r1;
    out[(size_t)(cbase + cc + 4) * DIM + j] = r2;
    out[(size_t)(cbase + cc + 6) * DIM + j] = r3;
}

extern "C" void kernel_launch(void* const* d_in, const int* in_sizes, int n_in,
                              void* d_out, int out_size, void* d_ws, size_t ws_size,
                              hipStream_t stream) {
    const float* loc  = (const float*)d_in[0];
    const float* W    = (const float*)d_in[1];
    const float* bias = (const float*)d_in[2];
    const int*   esrc = (const int*)d_in[3];
    const int*   edst = (const int*)d_in[4];
    float* out = (float*)d_out;

    const int threads = 256;
    const int eblocks = (N_EDGES + threads - 1) / threads;

    // path A' : counting sort, zero global atomics
    size_t need_cs   = ((size_t)2 * N_EDGES + (size_t)NB * N_CAT + 2 * PAD + DIM * DIM) * sizeof(int);
    // path A : rank via returning atomics
    size_t need_rank = ((size_t)2 * N_EDGES + 2 * PAD + DIM * DIM) * sizeof(int);

    if (ws_size >= need_cs) {
        int*   rank    = (int*)d_ws;                       // [N_EDGES]
        int*   csr_src = rank + N_EDGES;                   // [N_EDGES]
        int*   bhist   = csr_src + N_EDGES;                // [NB * N_CAT]
        int*   tot     = bhist + (size_t)NB * N_CAT;       // [PAD]
        int*   offsets = tot + PAD;                        // [N_CAT+1]
        float* WT      = (float*)(offsets + PAD);          // [DIM*DIM]

        transpose_kernel<<<DIM, DIM, 0, stream>>>(W, WT);
        blockhist_kernel<<<NB, 1024, 0, stream>>>(edst, rank, bhist);
        blockscan_kernel<<<(N_CAT + 255) / 256, 256, 0, stream>>>(bhist, tot);
        scan_kernel<<<1, 1024, 0, stream>>>(tot, offsets);
        fill2_kernel<<<eblocks, threads, 0, stream>>>(esrc, edst, rank, offsets, bhist, csr_src);
        agg_fused_kernel<<<N_CAT, 256, 0, stream>>>(loc, csr_src, offsets, WT, bias, out);
    } else if (ws_size >= need_rank) {
        int* counts  = (int*)d_ws;                 // [PAD]
        int* offsets = counts + PAD;               // [N_CAT+1]
        float* WT    = (float*)(offsets + PAD);    // [DIM*DIM]
        int* rank    = (int*)(WT + DIM * DIM);     // [N_EDGES]
        int* csr_src = rank + N_EDGES;             // [N_EDGES]

        hipMemsetAsync(counts, 0, (size_t)PAD * sizeof(int), stream);
        transpose_kernel<<<DIM, DIM, 0, stream>>>(W, WT);
        hist_rank_kernel<<<eblocks, threads, 0, stream>>>(edst, counts, rank, N_EDGES);
        scan_kernel<<<1, 1024, 0, stream>>>(counts, offsets);
        fill_rank_kernel<<<eblocks, threads, 0, stream>>>(esrc, edst, rank, offsets, csr_src, N_EDGES);
        agg_fused_kernel<<<N_CAT, 256, 0, stream>>>(loc, csr_src, offsets, WT, bias, out);
    } else {
        int n = N_CAT * DIM;
        zero_kernel<<<(n + 255) / 256, 256, 0, stream>>>(out, n);
        scatter_atomic_kernel<<<N_EDGES, DIM, 0, stream>>>(loc, esrc, edst, out);
        gemm_lrelu_kernel<<<N_CAT / CATS_PER_BLOCK, 256, 0, stream>>>(out, W, bias, out);
    }
}